// Round 5
// baseline (213.354 us; speedup 1.0000x reference)
//
#include <hip/hip_runtime.h>
#include <math.h>

#define TOKENS 16384
#define HIDDEN 2048
#define BM 256
#define BN 256
#define BK 64
#define NT (HIDDEN / BK)     // 32 K-tiles per pass
#define NVT (2 * NT)         // 64 virtual K-tiles (2 passes)
#define PASS_ROWS (32 * BM)  // 8192 rows between pass 0 and pass 1

typedef __attribute__((ext_vector_type(4))) float f32x4;
typedef __attribute__((ext_vector_type(8))) short s16x8;

__device__ __forceinline__ unsigned short f2bf(float f) {
  unsigned int u = __float_as_uint(f);
  u += 0x7fffu + ((u >> 16) & 1u);   // round-to-nearest-even
  return (unsigned short)(u >> 16);
}

// tanh-approx GELU via raw v_exp_f32 + v_rcp_f32; |err vs erf-gelu| ~1e-3.
__device__ __forceinline__ float fast_gelu(float y) {
  float t = y * fmaf(y * y, 0.044715f, 1.0f);
  float e = __builtin_amdgcn_exp2f(-2.3022082f * t);
  return y * __builtin_amdgcn_rcpf(1.0f + e);
}

// ---------------- kernel 0: W fp32 -> bf16 ----------------
__global__ __launch_bounds__(256) void wconv_kernel(const float* __restrict__ W,
                                                    unsigned short* __restrict__ Wb) {
  const int n4 = (HIDDEN * HIDDEN) / 4;
  for (int i = blockIdx.x * 256 + threadIdx.x; i < n4; i += gridDim.x * 256) {
    float4 v = *(const float4*)(W + (size_t)i * 4);
    ushort4 o;
    o.x = f2bf(v.x); o.y = f2bf(v.y); o.z = f2bf(v.z); o.w = f2bf(v.w);
    *(ushort4*)(Wb + (size_t)i * 4) = o;
  }
}

// ---------------- kernel 1: LayerNorm fp32 -> bf16, one block per row ----------------
__global__ __launch_bounds__(256) void ln_kernel(const float* __restrict__ x,
                                                 const float* __restrict__ gamma,
                                                 const float* __restrict__ beta,
                                                 unsigned short* __restrict__ xn) {
  const int row = blockIdx.x;
  const int t = threadIdx.x;
  const int wave = t >> 6, lane = t & 63;
  const float* xr = x + (size_t)row * HIDDEN + t * 8;
  float4 v0 = *(const float4*)(xr);
  float4 v1 = *(const float4*)(xr + 4);
  float xv[8] = {v0.x, v0.y, v0.z, v0.w, v1.x, v1.y, v1.z, v1.w};

  float s = 0.f, ss = 0.f;
#pragma unroll
  for (int j = 0; j < 8; ++j) { s += xv[j]; ss = fmaf(xv[j], xv[j], ss); }

#pragma unroll
  for (int off = 32; off > 0; off >>= 1) {
    s += __shfl_xor(s, off, 64);
    ss += __shfl_xor(ss, off, 64);
  }
  __shared__ float rs[4], rss[4];
  if (lane == 0) { rs[wave] = s; rss[wave] = ss; }
  __syncthreads();
  s = rs[0] + rs[1] + rs[2] + rs[3];
  ss = rss[0] + rss[1] + rss[2] + rss[3];

  const float mean = s * (1.0f / HIDDEN);
  const float var = ss * (1.0f / HIDDEN) - mean * mean;
  const float rstd = rsqrtf(var + 1e-5f);

  float4 g0 = *(const float4*)(gamma + t * 8);
  float4 g1 = *(const float4*)(gamma + t * 8 + 4);
  float4 b0 = *(const float4*)(beta + t * 8);
  float4 b1 = *(const float4*)(beta + t * 8 + 4);
  float gv[8] = {g0.x, g0.y, g0.z, g0.w, g1.x, g1.y, g1.z, g1.w};
  float bv[8] = {b0.x, b0.y, b0.z, b0.w, b1.x, b1.y, b1.z, b1.w};

  union { unsigned short h[8]; uint4 q; } pk;
#pragma unroll
  for (int j = 0; j < 8; ++j)
    pk.h[j] = f2bf((xv[j] - mean) * rstd * gv[j] + bv[j]);
  *(uint4*)(xn + (size_t)row * HIDDEN + t * 8) = pk.q;
}

// ---------------- kernel 2: persistent 256x256 8-phase bf16 GEMM + bias + fast GELU ----
// Grid = 256 blocks (1/CU). Each block computes TWO output M-tiles (same tn) as one
// seamless 64-virtual-K-tile pipeline. Two static accumulator sets (accA pass 0,
// accB pass 1). Pass-0 results are flushed SPREAD: 4 stores/thread per pass-1 K-tile
// (static chunk via 32-case switch), issued right after p3 so each chunk is a full
// K-tile old (L2-acked) before the next counted vmcnt(4) — no vmcnt poisoning.
// LDS 128 KiB: 2 buf x {A,B} x 2 half x 2 quarter x 8KB. XOR swizzle ((row&7)<<4) on
// gather source AND ds_read side. Counted vmcnt(4) per K-tile; setprio around MFMA.

#define GLOAD(gp, lp) __builtin_amdgcn_global_load_lds( \
    (const __attribute__((address_space(1))) unsigned int*)(gp), \
    (__attribute__((address_space(3))) unsigned int*)(lp), 16, 0, 0)

__global__ __launch_bounds__(512, 1) void gemm_kernel(const unsigned short* __restrict__ A,
                                                      const unsigned short* __restrict__ B,
                                                      const float* __restrict__ bias,
                                                      float* __restrict__ out) {
  __shared__ __attribute__((aligned(16))) char lds[131072];

  const int tid = threadIdx.x;
  const int lane = tid & 63;
  const int wave = tid >> 6;
  const int fr = lane & 15, hi = lane >> 4;

  // XCD-aware swizzle: 256 WGs, 256 % 8 == 0 -> bijective
  const int wg = blockIdx.x;
  const int swz = (wg & 7) * 32 + (wg >> 3);
  const int tm = swz >> 3, tn = swz & 7;   // 32 M-tile pairs x 8 N-tiles
  const int row0 = tm * BM, col0 = tn * BN;

  const int wmi = wave >> 2;        // wave M index (0..1)
  const int wni = wave & 3;         // wave N index (0..3)
  const int hB = wni >> 1, gB = wni & 1;

  // ---- staging geometry (per-lane gather, pre-swizzled source) ----
  const int rho = tid >> 3, sig = tid & 7;
  const int colgrp = ((sig ^ (rho & 7)) << 3);                 // k-element offset
  const unsigned short* Ap = A + (size_t)(row0 + rho) * HIDDEN + colgrp;
  const unsigned short* Bp = B + (size_t)(col0 + ((rho >> 5) << 6) + (rho & 31)) * HIDDEN + colgrp;
  const int ldsWaveOff = wave << 10;                            // 64 lanes * 16B

  // ---- ds_read per-lane constants (swizzled slot bytes for kk=0,1) ----
  const int s0 = ((hi ^ (fr & 7)) << 4);
  const int s1 = (((4 + hi) ^ (fr & 7)) << 4);
  const int aRowB = fr << 7;                        // fr*128
  const int bRowB = (((gB << 5) + fr) << 7);        // (gB*32+fr)*128

  auto stageA = [&](int vt, int bufd, int qm) {     // 2 calls: both halves of quarter qm
    const int vc = vt < NVT ? vt : NVT - 1;
    const unsigned short* g = Ap + (size_t)(vc >> 5) * ((size_t)PASS_ROWS * HIDDEN)
                                 + (size_t)(qm << 6) * HIDDEN + (vc & 31) * BK;
    GLOAD(g, lds + ((((bufd << 2) | qm) << 13)) + ldsWaveOff);
    GLOAD(g + (size_t)128 * HIDDEN, lds + ((((bufd << 2) | 2 | qm) << 13)) + ldsWaveOff);
  };
  auto stageB = [&](int vt, int bufd, int qn) {     // B identical across passes (same tn)
    const int vc = vt < NVT ? vt : NVT - 1;
    const unsigned short* g = Bp + (size_t)(qn << 5) * HIDDEN + (vc & 31) * BK;
    GLOAD(g, lds + 65536 + ((((bufd << 2) | qn) << 13)) + ldsWaveOff);
    GLOAD(g + (size_t)128 * HIDDEN, lds + 65536 + ((((bufd << 2) | 2 | qn) << 13)) + ldsWaveOff);
  };

  s16x8 a[4][2], b[2][2];

  // one virtual K-tile: 4 phases, counted vmcnt(4) at p3 boundary
  auto ktile = [&](int t, f32x4 (&acc)[2][4][4]) {
    const int buf = t & 1;
    const char* Abase = lds + (((buf << 2) | (wmi << 1)) << 13);
    const char* Bbase = lds + 65536 + (((buf << 2) | (hB << 1)) << 13);

    // ===== p0: quadrant (qm=0, qn=0) =====
#pragma unroll
    for (int mi = 0; mi < 4; ++mi) {
      a[mi][0] = *(const s16x8*)(Abase + mi * 2048 + aRowB + s0);
      a[mi][1] = *(const s16x8*)(Abase + mi * 2048 + aRowB + s1);
    }
#pragma unroll
    for (int nj = 0; nj < 2; ++nj) {
      b[nj][0] = *(const s16x8*)(Bbase + nj * 2048 + bRowB + s0);
      b[nj][1] = *(const s16x8*)(Bbase + nj * 2048 + bRowB + s1);
    }
    stageA(t + 1, buf ^ 1, 1);
    asm volatile("s_waitcnt lgkmcnt(8)" ::: "memory");
    __builtin_amdgcn_s_barrier();
    asm volatile("s_waitcnt lgkmcnt(0)" ::: "memory");
    __builtin_amdgcn_s_setprio(1);
#pragma unroll
    for (int mi = 0; mi < 4; ++mi)
#pragma unroll
      for (int nj = 0; nj < 2; ++nj)
#pragma unroll
        for (int kk = 0; kk < 2; ++kk)
          acc[0][mi][nj] = __builtin_amdgcn_mfma_f32_16x16x32_bf16(a[mi][kk], b[nj][kk], acc[0][mi][nj], 0, 0, 0);
    __builtin_amdgcn_s_setprio(0);
    __builtin_amdgcn_s_barrier();

    // ===== p1: quadrant (qm=0, qn=1) — reuse a =====
#pragma unroll
    for (int nj = 0; nj < 2; ++nj) {
      b[nj][0] = *(const s16x8*)(Bbase + 8192 + nj * 2048 + bRowB + s0);
      b[nj][1] = *(const s16x8*)(Bbase + 8192 + nj * 2048 + bRowB + s1);
    }
    stageB(t + 1, buf ^ 1, 0);
    __builtin_amdgcn_s_barrier();
    asm volatile("s_waitcnt lgkmcnt(0)" ::: "memory");
    __builtin_amdgcn_s_setprio(1);
#pragma unroll
    for (int mi = 0; mi < 4; ++mi)
#pragma unroll
      for (int nj = 0; nj < 2; ++nj)
#pragma unroll
        for (int kk = 0; kk < 2; ++kk)
          acc[0][mi][2 + nj] = __builtin_amdgcn_mfma_f32_16x16x32_bf16(a[mi][kk], b[nj][kk], acc[0][mi][2 + nj], 0, 0, 0);
    __builtin_amdgcn_s_setprio(0);
    __builtin_amdgcn_s_barrier();

    // ===== p2: quadrant (qm=1, qn=1) — reuse b =====
#pragma unroll
    for (int mi = 0; mi < 4; ++mi) {
      a[mi][0] = *(const s16x8*)(Abase + 8192 + mi * 2048 + aRowB + s0);
      a[mi][1] = *(const s16x8*)(Abase + 8192 + mi * 2048 + aRowB + s1);
    }
    stageA(t + 2, buf, 0);
    asm volatile("s_waitcnt lgkmcnt(4)" ::: "memory");
    __builtin_amdgcn_s_barrier();
    asm volatile("s_waitcnt lgkmcnt(0)" ::: "memory");
    __builtin_amdgcn_s_setprio(1);
#pragma unroll
    for (int mi = 0; mi < 4; ++mi)
#pragma unroll
      for (int nj = 0; nj < 2; ++nj)
#pragma unroll
        for (int kk = 0; kk < 2; ++kk)
          acc[1][mi][2 + nj] = __builtin_amdgcn_mfma_f32_16x16x32_bf16(a[mi][kk], b[nj][kk], acc[1][mi][2 + nj], 0, 0, 0);
    __builtin_amdgcn_s_setprio(0);
    __builtin_amdgcn_s_barrier();

    // ===== p3: quadrant (qm=1, qn=0) — reuse a; K-tile boundary vmcnt =====
#pragma unroll
    for (int nj = 0; nj < 2; ++nj) {
      b[nj][0] = *(const s16x8*)(Bbase + nj * 2048 + bRowB + s0);
      b[nj][1] = *(const s16x8*)(Bbase + nj * 2048 + bRowB + s1);
    }
    stageB(t + 2, buf, 1);
    asm volatile("s_waitcnt vmcnt(4)" ::: "memory");   // counted: next vtile landed, 4 in flight
    __builtin_amdgcn_s_barrier();
    asm volatile("s_waitcnt lgkmcnt(0)" ::: "memory");
    __builtin_amdgcn_s_setprio(1);
#pragma unroll
    for (int mi = 0; mi < 4; ++mi)
#pragma unroll
      for (int nj = 0; nj < 2; ++nj)
#pragma unroll
        for (int kk = 0; kk < 2; ++kk)
          acc[1][mi][nj] = __builtin_amdgcn_mfma_f32_16x16x32_bf16(a[mi][kk], b[nj][kk], acc[1][mi][nj], 0, 0, 0);
    __builtin_amdgcn_s_setprio(0);
    __builtin_amdgcn_s_barrier();
  };

  // ---- prologue: vtile0 fully + vtile1's first 2 quarters, steady-state age order ----
  stageA(0, 0, 0); stageB(0, 0, 1); stageA(0, 0, 1); stageB(0, 0, 0);
  stageA(1, 1, 0); stageB(1, 1, 1);
  asm volatile("s_waitcnt vmcnt(4)" ::: "memory");   // vtile0's 8 calls landed
  __builtin_amdgcn_s_barrier();

  // ================= pass 0 =================
  f32x4 accA[2][4][4] = {};
  for (int t = 0; t < NT; ++t) ktile(t, accA);

  // bias per-column values (reused by both flushes)
  float bcol[4];
#pragma unroll
  for (int ni = 0; ni < 4; ++ni)
    bcol[ni] = bias[col0 + (wni << 6) + ni * 16 + fr];

  // spread-flush chunk: all indices LITERAL (rule #20); 4 stores, issued after p3
  // so the chunk is a full K-tile (~2500 cyc) old before the next vmcnt(4).
#define FCHUNK(QM, MI, NI) { \
    const int c_ = col0 + (wni << 6) + (NI) * 16 + fr; \
    _Pragma("unroll") \
    for (int j = 0; j < 4; ++j) { \
      const int r_ = row0 + wmi * 128 + (QM) * 64 + (MI) * 16 + hi * 4 + j; \
      float y_ = accA[QM][MI][NI][j] + bcol[NI]; \
      out[(size_t)r_ * HIDDEN + c_] = fast_gelu(y_); \
    } }

  // ================= pass 1 (accB) + spread flush of accA =================
  f32x4 accB[2][4][4] = {};
  for (int tc = 0; tc < NT; ++tc) {
    ktile(NT + tc, accB);
    switch (tc) {
      case  0: FCHUNK(0,0,0); break;  case  1: FCHUNK(0,0,1); break;
      case  2: FCHUNK(0,0,2); break;  case  3: FCHUNK(0,0,3); break;
      case  4: FCHUNK(0,1,0); break;  case  5: FCHUNK(0,1,1); break;
      case  6: FCHUNK(0,1,2); break;  case  7: FCHUNK(0,1,3); break;
      case  8: FCHUNK(0,2,0); break;  case  9: FCHUNK(0,2,1); break;
      case 10: FCHUNK(0,2,2); break;  case 11: FCHUNK(0,2,3); break;
      case 12: FCHUNK(0,3,0); break;  case 13: FCHUNK(0,3,1); break;
      case 14: FCHUNK(0,3,2); break;  case 15: FCHUNK(0,3,3); break;
      case 16: FCHUNK(1,0,0); break;  case 17: FCHUNK(1,0,1); break;
      case 18: FCHUNK(1,0,2); break;  case 19: FCHUNK(1,0,3); break;
      case 20: FCHUNK(1,1,0); break;  case 21: FCHUNK(1,1,1); break;
      case 22: FCHUNK(1,1,2); break;  case 23: FCHUNK(1,1,3); break;
      case 24: FCHUNK(1,2,0); break;  case 25: FCHUNK(1,2,1); break;
      case 26: FCHUNK(1,2,2); break;  case 27: FCHUNK(1,2,3); break;
      case 28: FCHUNK(1,3,0); break;  case 29: FCHUNK(1,3,1); break;
      case 30: FCHUNK(1,3,2); break;  case 31: FCHUNK(1,3,3); break;
    }
  }

  asm volatile("s_waitcnt vmcnt(0)" ::: "memory");   // drain clamped tail prefetches

  // ---- final flush: pass-1 tile (rows + PASS_ROWS) ----
#pragma unroll
  for (int qm = 0; qm < 2; ++qm)
#pragma unroll
    for (int mi = 0; mi < 4; ++mi)
#pragma unroll
      for (int ni = 0; ni < 4; ++ni) {
        const int c = col0 + (wni << 6) + ni * 16 + fr;
#pragma unroll
        for (int j = 0; j < 4; ++j) {
          const int r = row0 + PASS_ROWS + wmi * 128 + qm * 64 + mi * 16 + hi * 4 + j;
          float y = accB[qm][mi][ni][j] + bcol[ni];
          out[(size_t)r * HIDDEN + c] = fast_gelu(y);
        }
      }
}

extern "C" void kernel_launch(void* const* d_in, const int* in_sizes, int n_in,
                              void* d_out, int out_size, void* d_ws, size_t ws_size,
                              hipStream_t stream) {
  const float* x     = (const float*)d_in[0];
  const float* gamma = (const float*)d_in[1];
  const float* beta  = (const float*)d_in[2];
  const float* W     = (const float*)d_in[3];
  const float* bias  = (const float*)d_in[4];
  float* out = (float*)d_out;

  unsigned short* xn = (unsigned short*)d_ws;
  unsigned short* wb = (unsigned short*)((char*)d_ws + (size_t)TOKENS * HIDDEN * 2);

  hipLaunchKernelGGL(wconv_kernel, dim3(1024), dim3(256), 0, stream, W, wb);
  hipLaunchKernelGGL(ln_kernel, dim3(TOKENS), dim3(256), 0, stream, x, gamma, beta, xn);
  hipLaunchKernelGGL(gemm_kernel, dim3((TOKENS / BM / 2) * (HIDDEN / BN)), dim3(512), 0, stream,
                     xn, wb, bias, out);
}

// Round 6
// 180.355 us; speedup vs baseline: 1.1830x; 1.1830x over previous
//
#include <hip/hip_runtime.h>
#include <math.h>

#define TOKENS 16384
#define HIDDEN 2048
#define BM 256
#define BN 256
#define BK 64
#define NT (HIDDEN / BK)   // 32 K-tiles

typedef __attribute__((ext_vector_type(4))) float f32x4;
typedef __attribute__((ext_vector_type(8))) short s16x8;

__device__ __forceinline__ unsigned short f2bf(float f) {
  unsigned int u = __float_as_uint(f);
  u += 0x7fffu + ((u >> 16) & 1u);   // round-to-nearest-even
  return (unsigned short)(u >> 16);
}

// tanh-approx GELU via raw v_exp_f32 + v_rcp_f32; |err vs erf-gelu| ~1e-3.
__device__ __forceinline__ float fast_gelu(float y) {
  float t = y * fmaf(y * y, 0.044715f, 1.0f);
  float e = __builtin_amdgcn_exp2f(-2.3022082f * t);
  return y * __builtin_amdgcn_rcpf(1.0f + e);
}

// ---------------- kernel 0: W fp32 -> bf16 ----------------
__global__ __launch_bounds__(256) void wconv_kernel(const float* __restrict__ W,
                                                    unsigned short* __restrict__ Wb) {
  const int n4 = (HIDDEN * HIDDEN) / 4;
  for (int i = blockIdx.x * 256 + threadIdx.x; i < n4; i += gridDim.x * 256) {
    float4 v = *(const float4*)(W + (size_t)i * 4);
    ushort4 o;
    o.x = f2bf(v.x); o.y = f2bf(v.y); o.z = f2bf(v.z); o.w = f2bf(v.w);
    *(ushort4*)(Wb + (size_t)i * 4) = o;
  }
}

// ---------------- kernel 1: LayerNorm fp32 -> bf16, one block per row ----------------
__global__ __launch_bounds__(256) void ln_kernel(const float* __restrict__ x,
                                                 const float* __restrict__ gamma,
                                                 const float* __restrict__ beta,
                                                 unsigned short* __restrict__ xn) {
  const int row = blockIdx.x;
  const int t = threadIdx.x;
  const int wave = t >> 6, lane = t & 63;
  const float* xr = x + (size_t)row * HIDDEN + t * 8;
  float4 v0 = *(const float4*)(xr);
  float4 v1 = *(const float4*)(xr + 4);
  float xv[8] = {v0.x, v0.y, v0.z, v0.w, v1.x, v1.y, v1.z, v1.w};

  float s = 0.f, ss = 0.f;
#pragma unroll
  for (int j = 0; j < 8; ++j) { s += xv[j]; ss = fmaf(xv[j], xv[j], ss); }

#pragma unroll
  for (int off = 32; off > 0; off >>= 1) {
    s += __shfl_xor(s, off, 64);
    ss += __shfl_xor(ss, off, 64);
  }
  __shared__ float rs[4], rss[4];
  if (lane == 0) { rs[wave] = s; rss[wave] = ss; }
  __syncthreads();
  s = rs[0] + rs[1] + rs[2] + rs[3];
  ss = rss[0] + rss[1] + rss[2] + rss[3];

  const float mean = s * (1.0f / HIDDEN);
  const float var = ss * (1.0f / HIDDEN) - mean * mean;
  const float rstd = rsqrtf(var + 1e-5f);

  float4 g0 = *(const float4*)(gamma + t * 8);
  float4 g1 = *(const float4*)(gamma + t * 8 + 4);
  float4 b0 = *(const float4*)(beta + t * 8);
  float4 b1 = *(const float4*)(beta + t * 8 + 4);
  float gv[8] = {g0.x, g0.y, g0.z, g0.w, g1.x, g1.y, g1.z, g1.w};
  float bv[8] = {b0.x, b0.y, b0.z, b0.w, b1.x, b1.y, b1.z, b1.w};

  union { unsigned short h[8]; uint4 q; } pk;
#pragma unroll
  for (int j = 0; j < 8; ++j)
    pk.h[j] = f2bf((xv[j] - mean) * rstd * gv[j] + bv[j]);
  *(uint4*)(xn + (size_t)row * HIDDEN + t * 8) = pk.q;
}

// ---------------- kernel 2: 256x256 2-fat-phase bf16 GEMM + bias + fast GELU ----------
// A[M,K] * B[N,K]^T. 512 threads = 8 waves (2M x 4N), per-wave output 128x64.
// vs the verified 4-phase template: phases merged to 2 square phases (64 rows x full
// 64-col wave width). All 4 B fragments held in registers across both phases ->
// LDS traffic 28->24 KB/wave/K-tile, barriers 8->4/K-tile. Counted vmcnt(6)/K-tile.
// Region-safety: P0 stages A(t+1,qm1)->buf^1 (readers drained at t-1 P1); P1 stages
// B(t+2)+A(t+2,qm0)->buf (all consumed in this tile's P0, drained at P0's barrier).
// LDS 128 KiB: 2 buf x {A,B} x 2 half x 2 quarter x 8KB. XOR swizzle ((row&7)<<4) on
// gather source AND ds_read side. XCD-aware block swizzle. setprio around MFMA.

#define GLOAD(gp, lp) __builtin_amdgcn_global_load_lds( \
    (const __attribute__((address_space(1))) unsigned int*)(gp), \
    (__attribute__((address_space(3))) unsigned int*)(lp), 16, 0, 0)

__global__ __launch_bounds__(512, 1) void gemm_kernel(const unsigned short* __restrict__ A,
                                                      const unsigned short* __restrict__ B,
                                                      const float* __restrict__ bias,
                                                      float* __restrict__ out) {
  __shared__ __attribute__((aligned(16))) char lds[131072];

  const int tid = threadIdx.x;
  const int lane = tid & 63;
  const int wave = tid >> 6;
  const int fr = lane & 15, hi = lane >> 4;

  // XCD-aware swizzle: 512 WGs, 512 % 8 == 0 -> bijective
  const int wg = blockIdx.x;
  const int swz = (wg & 7) * 64 + (wg >> 3);
  const int tm = swz >> 3, tn = swz & 7;   // 64 M-tiles x 8 N-tiles
  const int row0 = tm * BM, col0 = tn * BN;

  const int wmi = wave >> 2;        // wave M index (0..1)
  const int wni = wave & 3;         // wave N index (0..3)
  const int hB = wni >> 1, gB = wni & 1;

  // ---- staging geometry (per-lane gather, pre-swizzled source) ----
  const int rho = tid >> 3, sig = tid & 7;
  const int colgrp = ((sig ^ (rho & 7)) << 3);                 // k-element offset
  const unsigned short* Ap = A + (size_t)(row0 + rho) * HIDDEN + colgrp;
  const unsigned short* Bp = B + (size_t)(col0 + ((rho >> 5) << 6) + (rho & 31)) * HIDDEN + colgrp;
  const int ldsWaveOff = wave << 10;                            // 64 lanes * 16B

  // ---- ds_read per-lane constants (swizzled slot bytes for kk=0,1) ----
  const int s0 = ((hi ^ (fr & 7)) << 4);
  const int s1 = (((4 + hi) ^ (fr & 7)) << 4);
  const int aRowB = fr << 7;                        // fr*128
  const int bRowB = (((gB << 5) + fr) << 7);        // (gB*32+fr)*128

  auto stageA = [&](int tt, int bufd, int qm) {     // 2 calls: both halves of quarter qm
    const int tc = tt < NT ? tt : NT - 1;
    const unsigned short* g = Ap + (size_t)(qm << 6) * HIDDEN + tc * BK;
    GLOAD(g, lds + ((((bufd << 2) | qm) << 13)) + ldsWaveOff);
    GLOAD(g + (size_t)128 * HIDDEN, lds + ((((bufd << 2) | 2 | qm) << 13)) + ldsWaveOff);
  };
  auto stageB = [&](int tt, int bufd, int qn) {
    const int tc = tt < NT ? tt : NT - 1;
    const unsigned short* g = Bp + (size_t)(qn << 5) * HIDDEN + tc * BK;
    GLOAD(g, lds + 65536 + ((((bufd << 2) | qn) << 13)) + ldsWaveOff);
    GLOAD(g + (size_t)128 * HIDDEN, lds + 65536 + ((((bufd << 2) | 2 | qn) << 13)) + ldsWaveOff);
  };

  f32x4 acc[2][4][4] = {};
  s16x8 a[4][2], b[4][2];

  // ---- prologue: tile0 {B0,B1,A0,A1} + tile1 {B0,B1,A0}; A1(1) comes in tile0's P0 ----
  stageB(0, 0, 0); stageB(0, 0, 1); stageA(0, 0, 0); stageA(0, 0, 1);
  stageB(1, 1, 0); stageB(1, 1, 1); stageA(1, 1, 0);
  asm volatile("s_waitcnt vmcnt(6)" ::: "memory");   // tile0's 8 calls landed, 6 in flight
  __builtin_amdgcn_s_barrier();

  for (int t = 0; t < NT; ++t) {
    const int buf = t & 1;
    const char* Abase = lds + (((buf << 2) | (wmi << 1)) << 13);
    const char* Bbase = lds + 65536 + (((buf << 2) | (hB << 1)) << 13);

    // ===== P0: qm=0 rows x all 64 cols; read ALL B frags (kept for P1) =====
#pragma unroll
    for (int mi = 0; mi < 4; ++mi) {
      a[mi][0] = *(const s16x8*)(Abase + mi * 2048 + aRowB + s0);
      a[mi][1] = *(const s16x8*)(Abase + mi * 2048 + aRowB + s1);
    }
#pragma unroll
    for (int nj = 0; nj < 4; ++nj) {
      const char* bq = Bbase + (nj >> 1) * 8192 + (nj & 1) * 2048 + bRowB;
      b[nj][0] = *(const s16x8*)(bq + s0);
      b[nj][1] = *(const s16x8*)(bq + s1);
    }
    stageA(t + 1, buf ^ 1, 1);
    asm volatile("s_waitcnt lgkmcnt(8)" ::: "memory");
    __builtin_amdgcn_s_barrier();
    asm volatile("s_waitcnt lgkmcnt(0)" ::: "memory");
    __builtin_amdgcn_s_setprio(1);
#pragma unroll
    for (int mi = 0; mi < 4; ++mi)
#pragma unroll
      for (int nj = 0; nj < 4; ++nj)
#pragma unroll
        for (int kk = 0; kk < 2; ++kk)
          acc[0][mi][nj] = __builtin_amdgcn_mfma_f32_16x16x32_bf16(a[mi][kk], b[nj][kk], acc[0][mi][nj], 0, 0, 0);
    __builtin_amdgcn_s_setprio(0);
    __builtin_amdgcn_s_barrier();

    // ===== P1: qm=1 rows x all 64 cols; reuse b; stage t+2 {B0,B1,A0} -> buf =====
#pragma unroll
    for (int mi = 0; mi < 4; ++mi) {
      a[mi][0] = *(const s16x8*)(Abase + 8192 + mi * 2048 + aRowB + s0);
      a[mi][1] = *(const s16x8*)(Abase + 8192 + mi * 2048 + aRowB + s1);
    }
    stageB(t + 2, buf, 0);
    stageB(t + 2, buf, 1);
    stageA(t + 2, buf, 0);
    asm volatile("s_waitcnt vmcnt(6) lgkmcnt(4)" ::: "memory");  // tile t+1 landed, 6 in flight
    __builtin_amdgcn_s_barrier();
    asm volatile("s_waitcnt lgkmcnt(0)" ::: "memory");
    __builtin_amdgcn_s_setprio(1);
#pragma unroll
    for (int mi = 0; mi < 4; ++mi)
#pragma unroll
      for (int nj = 0; nj < 4; ++nj)
#pragma unroll
        for (int kk = 0; kk < 2; ++kk)
          acc[1][mi][nj] = __builtin_amdgcn_mfma_f32_16x16x32_bf16(a[mi][kk], b[nj][kk], acc[1][mi][nj], 0, 0, 0);
    __builtin_amdgcn_s_setprio(0);
    __builtin_amdgcn_s_barrier();
  }

  asm volatile("s_waitcnt vmcnt(0)" ::: "memory");   // drain clamped tail prefetches

  // ---- epilogue: bias + fast GELU, fp32 store ----
  float bcol[4];
#pragma unroll
  for (int ni = 0; ni < 4; ++ni)
    bcol[ni] = bias[col0 + (wni << 6) + ni * 16 + fr];

#pragma unroll
  for (int qm = 0; qm < 2; ++qm)
#pragma unroll
    for (int mi = 0; mi < 4; ++mi)
#pragma unroll
      for (int ni = 0; ni < 4; ++ni) {
        const int c = col0 + (wni << 6) + ni * 16 + fr;
#pragma unroll
        for (int j = 0; j < 4; ++j) {
          const int r = row0 + wmi * 128 + qm * 64 + mi * 16 + hi * 4 + j;
          float y = acc[qm][mi][ni][j] + bcol[ni];
          out[(size_t)r * HIDDEN + c] = fast_gelu(y);
        }
      }
}

extern "C" void kernel_launch(void* const* d_in, const int* in_sizes, int n_in,
                              void* d_out, int out_size, void* d_ws, size_t ws_size,
                              hipStream_t stream) {
  const float* x     = (const float*)d_in[0];
  const float* gamma = (const float*)d_in[1];
  const float* beta  = (const float*)d_in[2];
  const float* W     = (const float*)d_in[3];
  const float* bias  = (const float*)d_in[4];
  float* out = (float*)d_out;

  unsigned short* xn = (unsigned short*)d_ws;
  unsigned short* wb = (unsigned short*)((char*)d_ws + (size_t)TOKENS * HIDDEN * 2);

  hipLaunchKernelGGL(wconv_kernel, dim3(1024), dim3(256), 0, stream, W, wb);
  hipLaunchKernelGGL(ln_kernel, dim3(TOKENS), dim3(256), 0, stream, x, gamma, beta, xn);
  hipLaunchKernelGGL(gemm_kernel, dim3((TOKENS / BM) * (HIDDEN / BN)), dim3(512), 0, stream,
                     xn, wb, bias, out);
}